// Round 1
// baseline (193.306 us; speedup 1.0000x reference)
//
#include <hip/hip_runtime.h>
#include <math.h>

#define NROWS 2400
#define NCLS  91
#define L     128
#define KSUB  23
#define NKEEP 256

// LDS float layout:
// [0, 2944)      Csub[23][128]   (first 23 rows of the 128-pt DCT-II matrix)
// [2944, 5888)   M1t[23][128]    (M1t[v][i] = sum_u C[u][i]*coef[u][v])
// [5888, 6912)   Z: (a) 512-entry double cos table (4 KB)
//                   (b) coef[23][24]  (552 floats)
//                   (c) min/max reduce scratch (8 floats)
#define Z_OFF 5888
#define SMEM_FLOATS 6912

__global__ void __launch_bounds__(256)
postproc_kernel(const float* __restrict__ logits,
                const float* __restrict__ pboxes,
                const float* __restrict__ vecs,
                const int*   __restrict__ tsz,
                float* __restrict__ out)
{
    __shared__ float smem[SMEM_FLOATS];
    const int br  = blockIdx.x;
    const int tid = threadIdx.x;

    // ---------- Part A: scores / labels / boxes (wave 0 only, no barriers) ----------
    if (tid < 64) {
        const float* lrow = logits + (size_t)br * NCLS;
        float p = 1.0f / (1.0f + expf(-lrow[tid]));   // tid < 64 < 91: always valid
        int   bi = tid;
        if (tid < NCLS - 64) {                         // classes 64..90
            float p2 = 1.0f / (1.0f + expf(-lrow[tid + 64]));
            if (p2 > p) { p = p2; bi = tid + 64; }    // tie -> keep lower index
        }
        #pragma unroll
        for (int off = 32; off > 0; off >>= 1) {
            float po = __shfl_xor(p, off, 64);
            int   io = __shfl_xor(bi, off, 64);
            if (po > p || (po == p && io < bi)) { p = po; bi = io; }
        }
        if (tid == 0) {
            out[br] = p;                               // scores
            out[NROWS + br] = (float)bi;               // labels (as float)
            const int b = br / 300;
            const float W = (float)tsz[2 * b + 1];
            const float H = (float)tsz[2 * b + 0];
            const float4 bx = *(const float4*)(pboxes + (size_t)br * 4);
            float4 o;
            o.x = (bx.x - 0.5f * bx.z) * W;
            o.y = (bx.y - 0.5f * bx.w) * H;
            o.z = (bx.x + 0.5f * bx.z) * W;
            o.w = (bx.y + 0.5f * bx.w) * H;
            *(float4*)(out + 2 * NROWS + (size_t)br * 4) = o;   // boxes
        }
    }

    // ---------- Part B: build Csub (double precision, matches numpy f64 -> f32) ----------
    double* tab = (double*)&smem[Z_OFF];               // 5888*4 bytes, 8B aligned
    for (int t = tid; t < 512; t += 256)
        tab[t] = cos((3.14159265358979323846 / 256.0) * (double)t);
    __syncthreads();
    {
        const double s0 = sqrt(1.0 / 128.0);           // row 0 scale
        for (int idx = tid; idx < KSUB * L; idx += 256) {
            const int u = idx >> 7, m = idx & 127;
            float v;
            if (u == 0) v = (float)s0;
            else        v = (float)(0.125 * tab[((2 * m + 1) * u) & 511]); // sqrt(2/128)=0.125 exact
            smem[idx] = v;
        }
    }
    __syncthreads();                                    // cos table dead; Z reusable

    // ---------- Part C: scatter 256 zigzag coefficients into coef[23][24] ----------
    float* coef = &smem[Z_OFF];
    for (int idx = tid; idx < KSUB * 24; idx += 256) coef[idx] = 0.0f;
    __syncthreads();
    {
        const int k = tid;                              // exactly 256 threads = 256 coefs
        int s = 0;
        while ((s + 1) * (s + 2) / 2 <= k) ++s;         // diagonal index, s <= 22
        const int r = k - s * (s + 1) / 2;
        const int u  = (s & 1) ? r : (s - r);
        const int vv = (s & 1) ? (s - r) : r;
        coef[u * 24 + vv] = vecs[(size_t)br * NKEEP + k];
    }
    __syncthreads();

    // ---------- Part D: M1t[v][i] = sum_u Csub[u][i] * coef[u][v] ----------
    float* M1 = &smem[2944];
    for (int t = tid; t < KSUB * 32; t += 256) {
        const int v = t >> 5, i4 = (t & 31) << 2;
        float4 a = make_float4(0.f, 0.f, 0.f, 0.f);
        #pragma unroll
        for (int u = 0; u < KSUB; ++u) {
            const float4 cs = *(const float4*)&smem[u * L + i4];
            const float  cf = coef[u * 24 + v];
            a.x += cs.x * cf; a.y += cs.y * cf; a.z += cs.z * cf; a.w += cs.w * cf;
        }
        *(float4*)&M1[v * L + i4] = a;
    }
    __syncthreads();

    // ---------- Part E: re[i][j] = sum_v M1t[v][i] * Csub[v][j], 16x4 register tile ----------
    const int tx = tid & 31, ty = tid >> 5;
    const int j0 = tx << 2, i0 = ty << 4;
    float acc[16][4];
    #pragma unroll
    for (int r = 0; r < 16; ++r)
        #pragma unroll
        for (int q = 0; q < 4; ++q) acc[r][q] = 0.0f;

    for (int v = 0; v < KSUB; ++v) {
        const float4 c  = *(const float4*)&smem[v * L + j0];
        const float4 m0 = *(const float4*)&M1[v * L + i0];
        const float4 m1 = *(const float4*)&M1[v * L + i0 + 4];
        const float4 m2 = *(const float4*)&M1[v * L + i0 + 8];
        const float4 m3 = *(const float4*)&M1[v * L + i0 + 12];
        const float mv[16] = { m0.x, m0.y, m0.z, m0.w,
                               m1.x, m1.y, m1.z, m1.w,
                               m2.x, m2.y, m2.z, m2.w,
                               m3.x, m3.y, m3.z, m3.w };
        #pragma unroll
        for (int r = 0; r < 16; ++r) {
            acc[r][0] += mv[r] * c.x;
            acc[r][1] += mv[r] * c.y;
            acc[r][2] += mv[r] * c.z;
            acc[r][3] += mv[r] * c.w;
        }
    }

    // ---------- min/max reduce -> threshold ----------
    float mn = acc[0][0], mx = acc[0][0];
    #pragma unroll
    for (int r = 0; r < 16; ++r)
        #pragma unroll
        for (int q = 0; q < 4; ++q) {
            mn = fminf(mn, acc[r][q]);
            mx = fmaxf(mx, acc[r][q]);
        }
    #pragma unroll
    for (int off = 32; off > 0; off >>= 1) {
        mn = fminf(mn, __shfl_xor(mn, off, 64));
        mx = fmaxf(mx, __shfl_xor(mx, off, 64));
    }
    // coef (Z) last read before the Part D barrier; safe to reuse Z now
    const int w = tid >> 6;
    if ((tid & 63) == 0) { smem[Z_OFF + w] = mn; smem[Z_OFF + 4 + w] = mx; }
    __syncthreads();
    const float gmn = fminf(fminf(smem[Z_OFF + 0], smem[Z_OFF + 1]),
                            fminf(smem[Z_OFF + 2], smem[Z_OFF + 3]));
    const float gmx = fmaxf(fmaxf(smem[Z_OFF + 4], smem[Z_OFF + 5]),
                            fmaxf(smem[Z_OFF + 6], smem[Z_OFF + 7]));
    const float thr = (gmx + gmn) * 0.5f;

    // ---------- binarize + coalesced float4 stores ----------
    float* omask = out + 6 * NROWS + (size_t)br * (L * L);   // 14400 + br*16384
    #pragma unroll
    for (int r = 0; r < 16; ++r) {
        float4 o;
        o.x = acc[r][0] > thr ? 1.0f : 0.0f;
        o.y = acc[r][1] > thr ? 1.0f : 0.0f;
        o.z = acc[r][2] > thr ? 1.0f : 0.0f;
        o.w = acc[r][3] > thr ? 1.0f : 0.0f;
        *(float4*)&omask[(i0 + r) * L + j0] = o;
    }
}

extern "C" void kernel_launch(void* const* d_in, const int* in_sizes, int n_in,
                              void* d_out, int out_size, void* d_ws, size_t ws_size,
                              hipStream_t stream)
{
    const float* logits = (const float*)d_in[0];
    const float* pboxes = (const float*)d_in[1];
    const float* vecs   = (const float*)d_in[2];
    const int*   tsz    = (const int*)d_in[3];
    float* out = (float*)d_out;
    (void)d_ws; (void)ws_size; (void)in_sizes; (void)n_in; (void)out_size;

    postproc_kernel<<<dim3(NROWS), dim3(256), 0, stream>>>(logits, pboxes, vecs, tsz, out);
}